// Round 3
// baseline (109.486 us; speedup 1.0000x reference)
//
#include <hip/hip_runtime.h>
#include <math.h>

// Problem constants (match reference)
static constexpr int kB  = 128;
static constexpr int kN  = 8732;
static constexpr int kC  = 25;     // 4 loc + 21 cls
static constexpr int kNC = 21;     // num classes incl. background
static constexpr int TR  = 64;     // rows per wave-tile
static constexpr int WPB = 4;      // waves per block (256 threads)
static constexpr int TILES = (kN + TR - 1) / TR;      // 137 (136 full + 1x28)
static constexpr int BX    = (TILES + WPB - 1) / WPB; // 35

__global__ __launch_bounds__(128) void zero_num_kernel(float* __restrict__ numf) {
    int t = threadIdx.x;
    if (t < kB) numf[t] = 0.0f;
}

// No __syncthreads anywhere: each wave stages and consumes its own LDS slice.
__global__ __launch_bounds__(256) void decode_kernel(
    const float* __restrict__ logits,   // [B, N, 25]
    const float* __restrict__ anchors,  // [N, 4]
    float* __restrict__ boxes,          // [B, N, 4]
    float* __restrict__ scores,         // [B, N]
    float* __restrict__ classesf,       // [B, N]
    float* __restrict__ validf,         // [B, N]
    float* __restrict__ numf)           // [B]
{
    __shared__ float lds[WPB][TR * kC];   // 4 x 6.4 KB = 25.6 KB -> 6 blocks/CU

    const int wave = threadIdx.x >> 6;
    const int l    = threadIdx.x & 63;
    const int tile = blockIdx.x * WPB + wave;
    if (tile >= TILES) return;            // safe: no barriers in this kernel

    const int b     = blockIdx.y;
    const int row0  = tile * TR;
    const int nrows = min(TR, kN - row0); // 64 or 28
    const long grow0 = (long)b * kN + row0;   // grow0 % 4 == 0 -> 16B-aligned rows*25

    float* __restrict__ ldsw = lds[wave];

    // ---- Stage wave-private tile: 7 dwordx4 loads/lane, one latency exposure ----
    const float4* __restrict__ src4 = (const float4*)(logits + grow0 * kC);
    float4* dst4 = (float4*)ldsw;
    if (nrows == TR) {
        // 64*25 floats = 400 float4: 6 full rounds + 16 lanes tail
        float4 v[6];
        #pragma unroll
        for (int k = 0; k < 6; ++k) v[k] = src4[l + 64 * k];
        float4 vt;
        const bool tl = (l < 16);
        if (tl) vt = src4[384 + l];
        #pragma unroll
        for (int k = 0; k < 6; ++k) dst4[l + 64 * k] = v[k];
        if (tl) dst4[384 + l] = vt;
    } else {
        // tail tile: nrows*25/4 float4 (28*25/4 = 175), predicated
        const int nvec = nrows * kC / 4;
        #pragma unroll
        for (int k = 0; k < 7; ++k) {
            const int i = l + 64 * k;
            if (i < nvec) dst4[i] = src4[i];
        }
    }
    // compiler inserts lgkmcnt waits for same-wave ds_write -> ds_read

    bool valid = false;
    if (l < nrows) {
        const float* __restrict__ L = ldsw + l * kC;  // stride 25: all banks distinct
        const int n  = row0 + l;
        const long bn = grow0 + l;

        const float4 a = ((const float4*)anchors)[n]; // coalesced, L2/L3-resident
        const float cx = 0.5f * (a.x + a.z);
        const float cy = 0.5f * (a.y + a.w);
        const float w  = a.z - a.x;
        const float h  = a.w - a.y;

        const float xc = L[0] * w + cx;
        const float yc = L[1] * h + cy;
        const float bw = expf(L[2]) * w;
        const float bh = expf(L[3]) * h;

        const float x0 = fminf(fmaxf(xc - 0.5f * bw, 0.0f), 1.0f);
        const float y0 = fminf(fmaxf(yc - 0.5f * bh, 0.0f), 1.0f);
        const float x1 = fminf(fmaxf(xc + 0.5f * bw, 0.0f), 1.0f);
        const float y1 = fminf(fmaxf(yc + 0.5f * bh, 0.0f), 1.0f);

        // max/argmax over 21 classes, first-max tie-break (jnp.argmax)
        float best = L[4];
        int   bidx = 0;
        #pragma unroll
        for (int c = 1; c < kNC; ++c) {
            const float v = L[4 + c];
            if (v > best) { best = v; bidx = c; }
        }
        valid = (bidx != 0);

        ((float4*)boxes)[bn] = make_float4(x0, y0, x1, y1);  // unit-stride float4
        scores[bn]   = best;
        classesf[bn] = (float)bidx;
        validf[bn]   = valid ? 1.0f : 0.0f;
    }

    // one atomic per wave
    const unsigned long long m = __ballot(valid);
    if (l == 0 && m != 0ull)
        atomicAdd(&numf[b], (float)__popcll(m));
}

extern "C" void kernel_launch(void* const* d_in, const int* in_sizes, int n_in,
                              void* d_out, int out_size, void* d_ws, size_t ws_size,
                              hipStream_t stream) {
    const float* logits  = (const float*)d_in[0];
    const float* anchors = (const float*)d_in[1];

    float* out = (float*)d_out;
    const long BN = (long)kB * kN;
    float* boxes    = out;                 // 4*BN
    float* scores   = boxes + 4 * BN;      // BN
    float* classesf = scores + BN;         // BN
    float* validf   = classesf + BN;       // BN
    float* numf     = validf + BN;         // B

    zero_num_kernel<<<1, 128, 0, stream>>>(numf);
    dim3 grid(BX, kB);
    decode_kernel<<<grid, 256, 0, stream>>>(logits, anchors, boxes, scores,
                                            classesf, validf, numf);
}

// Round 4
// 28.313 us; speedup vs baseline: 3.8669x; 3.8669x over previous
//
#include <hip/hip_runtime.h>
#include <math.h>

// Problem constants (match reference)
static constexpr int kB  = 128;
static constexpr int kN  = 8732;
static constexpr int kC  = 25;     // 4 loc + 21 cls
static constexpr int kNC = 21;     // num classes incl. background
static constexpr int TR  = 64;     // rows per wave-tile
static constexpr int WPB = 4;      // waves per block (256 threads)
static constexpr int TILES = (kN + TR - 1) / TR;      // 137 (136 full + 1x28)
static constexpr int BX    = (TILES + WPB - 1) / WPB; // 35
static constexpr int PADT  = 144;  // padded tile stride in ws partials

__global__ __launch_bounds__(128) void zero_num_kernel(float* __restrict__ numf) {
    int t = threadIdx.x;
    if (t < kB) numf[t] = 0.0f;
}

// Wave-autonomous: each wave stages+consumes its own LDS slice, no barriers.
// part != nullptr: write per-wave popcount partial (no atomics).
// part == nullptr: legacy atomic fallback (requires numf pre-zeroed).
__global__ __launch_bounds__(256) void decode_kernel(
    const float* __restrict__ logits,   // [B, N, 25]
    const float* __restrict__ anchors,  // [N, 4]
    float* __restrict__ boxes,          // [B, N, 4]
    float* __restrict__ scores,         // [B, N]
    float* __restrict__ classesf,       // [B, N]
    float* __restrict__ validf,         // [B, N]
    float* __restrict__ numf,           // [B]
    float* __restrict__ part)           // [B][PADT] partials or nullptr
{
    __shared__ float lds[WPB][TR * kC];   // 4 x 6.4 KB = 25.6 KB

    const int wave = threadIdx.x >> 6;
    const int l    = threadIdx.x & 63;
    const int tile = blockIdx.x * WPB + wave;
    if (tile >= TILES) return;            // safe: no barriers in this kernel

    const int b     = blockIdx.y;
    const int row0  = tile * TR;
    const int nrows = min(TR, kN - row0); // 64 or 28
    const long grow0 = (long)b * kN + row0;   // grow0 % 4 == 0 -> 16B-aligned tile

    float* __restrict__ ldsw = lds[wave];

    // ---- Stage wave-private tile: dwordx4 loads, one latency exposure ----
    const float4* __restrict__ src4 = (const float4*)(logits + grow0 * kC);
    float4* dst4 = (float4*)ldsw;
    if (nrows == TR) {
        // 64*25 floats = 400 float4: 6 full rounds + 16-lane tail
        float4 v[6];
        #pragma unroll
        for (int k = 0; k < 6; ++k) v[k] = src4[l + 64 * k];
        float4 vt;
        const bool tl = (l < 16);
        if (tl) vt = src4[384 + l];
        #pragma unroll
        for (int k = 0; k < 6; ++k) dst4[l + 64 * k] = v[k];
        if (tl) dst4[384 + l] = vt;
    } else {
        const int nvec = nrows * kC / 4;  // 175 for the 28-row tail
        #pragma unroll
        for (int k = 0; k < 7; ++k) {
            const int i = l + 64 * k;
            if (i < nvec) dst4[i] = src4[i];
        }
    }

    bool valid = false;
    if (l < nrows) {
        const float* __restrict__ L = ldsw + l * kC;  // stride 25: conflict-free
        const int n  = row0 + l;
        const long bn = grow0 + l;

        const float4 a = ((const float4*)anchors)[n];
        const float cx = 0.5f * (a.x + a.z);
        const float cy = 0.5f * (a.y + a.w);
        const float w  = a.z - a.x;
        const float h  = a.w - a.y;

        const float xc = L[0] * w + cx;
        const float yc = L[1] * h + cy;
        const float bw = expf(L[2]) * w;
        const float bh = expf(L[3]) * h;

        const float x0 = fminf(fmaxf(xc - 0.5f * bw, 0.0f), 1.0f);
        const float y0 = fminf(fmaxf(yc - 0.5f * bh, 0.0f), 1.0f);
        const float x1 = fminf(fmaxf(xc + 0.5f * bw, 0.0f), 1.0f);
        const float y1 = fminf(fmaxf(yc + 0.5f * bh, 0.0f), 1.0f);

        // max/argmax over 21 classes, first-max tie-break (jnp.argmax)
        float best = L[4];
        int   bidx = 0;
        #pragma unroll
        for (int c = 1; c < kNC; ++c) {
            const float v = L[4 + c];
            if (v > best) { best = v; bidx = c; }
        }
        valid = (bidx != 0);

        ((float4*)boxes)[bn] = make_float4(x0, y0, x1, y1);
        scores[bn]   = best;
        classesf[bn] = (float)bidx;
        validf[bn]   = valid ? 1.0f : 0.0f;
    }

    const unsigned long long m = __ballot(valid);
    if (l == 0) {
        const float c = (float)__popcll(m);
        if (part) {
            part[(long)b * PADT + tile] = c;   // plain store, zero contention
        } else if (c > 0.0f) {
            atomicAdd(&numf[b], c);            // fallback path
        }
    }
}

__global__ __launch_bounds__(64) void reduce_num_kernel(
    const float* __restrict__ part,   // [B][PADT]
    float* __restrict__ numf)         // [B]
{
    const int b = blockIdx.x;
    const int l = threadIdx.x;
    float s = 0.0f;
    #pragma unroll
    for (int t = l; t < TILES; t += 64)   // 137 partials: 2-3 per lane
        s += part[(long)b * PADT + t];
    #pragma unroll
    for (int off = 32; off > 0; off >>= 1)
        s += __shfl_down(s, off);
    if (l == 0) numf[b] = s;
}

extern "C" void kernel_launch(void* const* d_in, const int* in_sizes, int n_in,
                              void* d_out, int out_size, void* d_ws, size_t ws_size,
                              hipStream_t stream) {
    const float* logits  = (const float*)d_in[0];
    const float* anchors = (const float*)d_in[1];

    float* out = (float*)d_out;
    const long BN = (long)kB * kN;
    float* boxes    = out;                 // 4*BN
    float* scores   = boxes + 4 * BN;      // BN
    float* classesf = scores + BN;         // BN
    float* validf   = classesf + BN;       // BN
    float* numf     = validf + BN;         // B

    const size_t need = (size_t)kB * PADT * sizeof(float);   // 73,728 B
    float* part = (ws_size >= need) ? (float*)d_ws : nullptr;

    if (!part) zero_num_kernel<<<1, 128, 0, stream>>>(numf);

    dim3 grid(BX, kB);
    decode_kernel<<<grid, 256, 0, stream>>>(logits, anchors, boxes, scores,
                                            classesf, validf, numf, part);
    if (part) reduce_num_kernel<<<kB, 64, 0, stream>>>(part, numf);
}